// Round 3
// baseline (22.020 us; speedup 1.0000x reference)
//
#include <hip/hip_runtime.h>
#include <hip/hip_bf16.h>

// LocalitySelfAttention collapses: diag(+1e9) => softmax is exactly identity
// => out = x @ (w_proj @ W_v)^T + b_proj, W_v = w_qkv[2C:3C,:].
// Kernel A: W_eff = w_proj @ W_v (fp32), stored bf16 in MFMA-B packed layout.
// Kernel B: [8192,256] x [256,256]^T GEMM via mfma_f32_16x16x32_bf16 + bias.
// v4: both kernels at 4 waves/SIMD for latency hiding.

#define C_DIM 256
#define M_ROWS 8192   // B*N = 2*4096

typedef __attribute__((ext_vector_type(8))) short short8;
typedef __attribute__((ext_vector_type(4))) float f32x4;

static __device__ __forceinline__ short f2bf(float f) {
    __hip_bfloat16 h = __float2bfloat16(f);   // RN
    return __builtin_bit_cast(short, h);
}

// ---- Kernel A: W_eff[n][k] = sum_c w_proj[n][c] * w_qkv[2C+c][k], packed ----
// Packed layout (matches B-fragment consumption in kernel B):
//   wpack[((nb*8 + kb)*64 + lane)*8 + i] = W_eff[nb*16+(lane&15)][kb*32+(lane>>4)*8+i]
// v4: 1024 threads/block; thread (cq,k) sums a 64-long c-quarter with 4
// independent accumulators; LDS reduce across the 4 quarters.
__global__ void __launch_bounds__(1024) weff_pack_kernel(
        const float* __restrict__ w_qkv,
        const float* __restrict__ w_proj,
        short* __restrict__ wpack) {
    __shared__ float part[4][C_DIM];
    const int tid = threadIdx.x;
    const int k  = tid & 255;       // k index
    const int cq = tid >> 8;        // c-quarter 0..3
    const int n  = blockIdx.x;      // 0..255 (output row of W_eff)
    const float* __restrict__ wv = w_qkv + 2 * C_DIM * C_DIM;  // V-projection rows
    const float* __restrict__ wp = w_proj + n * C_DIM;
    float a0 = 0.f, a1 = 0.f, a2 = 0.f, a3 = 0.f;
    const int c0 = cq * 64;
#pragma unroll 8
    for (int c = c0; c < c0 + 64; c += 4) {
        a0 += wp[c + 0] * wv[(size_t)(c + 0) * C_DIM + k];  // wp uniform (s_load)
        a1 += wp[c + 1] * wv[(size_t)(c + 1) * C_DIM + k];  // wv coalesced
        a2 += wp[c + 2] * wv[(size_t)(c + 2) * C_DIM + k];
        a3 += wp[c + 3] * wv[(size_t)(c + 3) * C_DIM + k];
    }
    part[cq][k] = (a0 + a1) + (a2 + a3);
    __syncthreads();
    if (tid < 256) {
        const float acc = (part[0][k] + part[1][k]) + (part[2][k] + part[3][k]);
        const int nb = n >> 4, ln = n & 15;
        const int kb = k >> 5, hi = (k >> 3) & 3, i = k & 7;
        const int lane = hi * 16 + ln;
        wpack[(size_t)(((nb * 8 + kb) * 64) + lane) * 8 + i] = f2bf(acc);
    }
}

// ---- Kernel B: out[m][n] = sum_k x[m][k]*W_eff[n][k] + b_proj[n] ----
// v4: 512-thread block = 8 waves, ALL on one 16-row strip (x re-reads are
// L1 hits); wave wid owns 2 n-blocks (32 cols). Grid=512 -> 4096 waves
// = 16 waves/CU = 4 waves/SIMD.
__global__ void __launch_bounds__(512) out_gemm_kernel(
        const float* __restrict__ x,
        const short* __restrict__ wpack,
        const float* __restrict__ b_proj,
        float* __restrict__ out) {
    const int lane = threadIdx.x & 63;
    const int wid  = threadIdx.x >> 6;          // 0..7
    const int lr = lane & 15;                   // row (A) / col (B,C)
    const int hi = lane >> 4;                   // k-group
    const int m0 = blockIdx.x * 16;             // this block's 16-row strip
    const int nb0 = wid * 2;                    // this wave's 2 n-blocks

    // A fragments: a[kb][j] = bf16(x[m0+lr][kb*32 + hi*8 + j])
    short8 a[8];
    const float* __restrict__ xr = x + (size_t)(m0 + lr) * C_DIM;
#pragma unroll
    for (int kb = 0; kb < 8; ++kb) {
        const f32x4* p = reinterpret_cast<const f32x4*>(xr + kb * 32 + hi * 8);
        f32x4 u = p[0];
        f32x4 v = p[1];
        short8 t;
#pragma unroll
        for (int j = 0; j < 4; ++j) {
            t[j]     = f2bf(u[j]);
            t[4 + j] = f2bf(v[j]);
        }
        a[kb] = t;
    }

    const short8* __restrict__ wp8 = reinterpret_cast<const short8*>(wpack);
#pragma unroll
    for (int nbi = 0; nbi < 2; ++nbi) {
        const int nb = nb0 + nbi;
        f32x4 acc = {0.f, 0.f, 0.f, 0.f};
#pragma unroll
        for (int kb = 0; kb < 8; ++kb) {
            short8 b = wp8[(nb * 8 + kb) * 64 + lane];
            acc = __builtin_amdgcn_mfma_f32_16x16x32_bf16(a[kb], b, acc, 0, 0, 0);
        }
        const float bias = b_proj[nb * 16 + lr];
        // C/D layout (measured): col = lane&15, row = (lane>>4)*4 + reg
#pragma unroll
        for (int r = 0; r < 4; ++r) {
            out[(size_t)(m0 + hi * 4 + r) * C_DIM + nb * 16 + lr] = acc[r] + bias;
        }
    }
}

extern "C" void kernel_launch(void* const* d_in, const int* in_sizes, int n_in,
                              void* d_out, int out_size, void* d_ws, size_t ws_size,
                              hipStream_t stream) {
    const float* x      = (const float*)d_in[0];   // [2,4096,256]
    const float* w_qkv  = (const float*)d_in[1];   // [768,256]
    const float* w_proj = (const float*)d_in[2];   // [256,256]
    const float* b_proj = (const float*)d_in[3];   // [256]
    // d_in[4] = temperature: softmax is exactly one-hot for any T>0 -> unused.
    short* wpack = (short*)d_ws;                   // 256*256 bf16 = 128 KB
    float* out = (float*)d_out;

    hipLaunchKernelGGL(weff_pack_kernel, dim3(256), dim3(1024), 0, stream,
                       w_qkv, w_proj, wpack);
    hipLaunchKernelGGL(out_gemm_kernel, dim3(M_ROWS / 16), dim3(512), 0, stream,
                       x, wpack, b_proj, out);
}